// Round 1
// baseline (1046.528 us; speedup 1.0000x reference)
//
#include <hip/hip_runtime.h>
#include <hip/hip_bf16.h>

#define N_NODES 50000
#define N_EDGES 800000
#define N_GRAPHS 256
#define IN_DIM 300
#define HID 256

// ---------------- CSR build ----------------

__global__ void count_deg(const int* __restrict__ dst, int* __restrict__ cnt, int E) {
    int e = blockIdx.x * 256 + threadIdx.x;
    if (e < E) atomicAdd(&cnt[dst[e]], 1);
}

__global__ void dinv_k(const int* __restrict__ cnt, float* __restrict__ dinv, int n) {
    int i = blockIdx.x * 256 + threadIdx.x;
    if (i < n) dinv[i] = rsqrtf((float)(cnt[i] + 1));  // +1 self-loop; deg>=1 always
}

__global__ void scan1(const int* __restrict__ cnt, int* __restrict__ rp,
                      int* __restrict__ bsums, int n) {
    __shared__ int s[256];
    int i = blockIdx.x * 256 + threadIdx.x;
    int v = (i < n) ? cnt[i] : 0;
    s[threadIdx.x] = v;
    __syncthreads();
    for (int off = 1; off < 256; off <<= 1) {
        int t = (threadIdx.x >= off) ? s[threadIdx.x - off] : 0;
        __syncthreads();
        s[threadIdx.x] += t;
        __syncthreads();
    }
    if (i < n) rp[i] = s[threadIdx.x] - v;  // exclusive
    if (threadIdx.x == 255) bsums[blockIdx.x] = s[255];
}

__global__ void scan2(int* __restrict__ bsums, int nb) {
    __shared__ int s[256];
    int v = (threadIdx.x < nb) ? bsums[threadIdx.x] : 0;
    s[threadIdx.x] = v;
    __syncthreads();
    for (int off = 1; off < 256; off <<= 1) {
        int t = (threadIdx.x >= off) ? s[threadIdx.x - off] : 0;
        __syncthreads();
        s[threadIdx.x] += t;
        __syncthreads();
    }
    if (threadIdx.x < nb) bsums[threadIdx.x] = s[threadIdx.x] - v;  // exclusive
}

__global__ void scan3(int* __restrict__ rp, int* __restrict__ cursor,
                      const int* __restrict__ bsums, int n) {
    int i = blockIdx.x * 256 + threadIdx.x;
    if (i < n) {
        int v = rp[i] + bsums[blockIdx.x];
        rp[i] = v;
        cursor[i] = v;
    }
}

__global__ void fill_csr(const int* __restrict__ src, const int* __restrict__ dst,
                         int* __restrict__ cursor, int* __restrict__ col, int E) {
    int e = blockIdx.x * 256 + threadIdx.x;
    if (e < E) {
        int d = dst[e];
        int p = atomicAdd(&cursor[d], 1);  // cursor starts at rp[d] -> absolute slot
        col[p] = src[e];
    }
}

// ---------------- fp32 GEMM: C[M,256] = A[M,K] @ W[K,256] ----------------
// 64x64 tile, 256 threads, 4x4 per thread.

__global__ __launch_bounds__(256) void gemm_f32(const float* __restrict__ A,
                                                const float* __restrict__ W,
                                                float* __restrict__ C, int M, int K) {
    const int N = 256;
    __shared__ float As[16][65];  // [k][row], +1 pad breaks store conflicts
    __shared__ float Ws[16][64];  // [k][col]
    int t = threadIdx.x;
    int tx = t & 15;    // col group (4 cols)
    int ty = t >> 4;    // row group (4 rows)
    int r0 = blockIdx.y * 64;
    int n0 = blockIdx.x * 64;
    int ar = t >> 4;    // 0..15 row-in-slab for A loads
    int ak = t & 15;    // k for A loads
    int wn = t & 63;    // col for W loads
    int wk = t >> 6;    // 0..3 k-in-slab for W loads

    float acc[4][4] = {};
    for (int k0 = 0; k0 < K; k0 += 16) {
#pragma unroll
        for (int i = 0; i < 4; ++i) {
            int row = r0 + ar + 16 * i;
            int kk = k0 + ak;
            As[ak][ar + 16 * i] = (row < M && kk < K) ? A[(size_t)row * K + kk] : 0.f;
        }
#pragma unroll
        for (int i = 0; i < 4; ++i) {
            int kk = k0 + wk + 4 * i;
            Ws[wk + 4 * i][wn] = (kk < K) ? W[(size_t)kk * N + n0 + wn] : 0.f;
        }
        __syncthreads();
#pragma unroll
        for (int k = 0; k < 16; ++k) {
            float a[4], b[4];
#pragma unroll
            for (int i = 0; i < 4; ++i) a[i] = As[k][ty * 4 + i];
#pragma unroll
            for (int j = 0; j < 4; ++j) b[j] = Ws[k][tx * 4 + j];
#pragma unroll
            for (int i = 0; i < 4; ++i)
#pragma unroll
                for (int j = 0; j < 4; ++j) acc[i][j] += a[i] * b[j];
        }
        __syncthreads();
    }
#pragma unroll
    for (int i = 0; i < 4; ++i) {
        int row = r0 + ty * 4 + i;
        if (row < M) {
#pragma unroll
            for (int j = 0; j < 4; ++j)
                C[(size_t)row * N + n0 + tx * 4 + j] = acc[i][j];
        }
    }
}

// ---------------- CSR aggregation: out[d] = dinv[d]*(dinv[d]*h[d] + sum dinv[s]*h[s]) + b

__global__ __launch_bounds__(256) void aggregate(const float* __restrict__ h,
                                                 float* __restrict__ out,
                                                 const int* __restrict__ rp,
                                                 const int* __restrict__ cnt,
                                                 const int* __restrict__ col,
                                                 const float* __restrict__ dinv,
                                                 const float* __restrict__ bias, int relu) {
    int n = blockIdx.x;
    int f = threadIdx.x;
    __shared__ int scol[256];
    __shared__ float sdi[256];
    float dv = dinv[n];
    float acc = dv * h[(size_t)n * HID + f];  // self-loop (dv applied again below)
    int start = rp[n], c = cnt[n];
    for (int base = 0; base < c; base += 256) {
        int e = base + threadIdx.x;
        if (e < c) {
            int s0 = col[start + e];
            scol[threadIdx.x] = s0;
            sdi[threadIdx.x] = dinv[s0];
        }
        __syncthreads();
        int m = min(256, c - base);
        for (int j = 0; j < m; ++j) {
            acc += sdi[j] * h[(size_t)scol[j] * HID + f];
        }
        __syncthreads();
    }
    float r = dv * acc + bias[f];
    if (relu) r = fmaxf(r, 0.f);
    out[(size_t)n * HID + f] = r;
}

// ---------------- mean pool per graph (batch sorted) ----------------

__global__ __launch_bounds__(256) void pool_k(const float* __restrict__ h,
                                              const int* __restrict__ batch,
                                              float* __restrict__ pooled, int n) {
    int g = blockIdx.x;
    int f = threadIdx.x;
    int lo = 0, hi = n;
    while (lo < hi) { int mid = (lo + hi) >> 1; if (batch[mid] < g) lo = mid + 1; else hi = mid; }
    int start = lo;
    lo = start; hi = n;
    while (lo < hi) { int mid = (lo + hi) >> 1; if (batch[mid] < g + 1) lo = mid + 1; else hi = mid; }
    int end = lo;
    float s = 0.f;
    for (int i = start; i < end; ++i) s += h[(size_t)i * HID + f];
    int c = end - start;
    pooled[g * HID + f] = s / (float)max(c, 1);
}

// ---------------- fused head: l1 -> softmax -> l2 -> softmax -> l3 ----------------

__global__ __launch_bounds__(256) void head_k(const float* __restrict__ pooled,
                                              const float* __restrict__ Wc1, const float* __restrict__ bc1,
                                              const float* __restrict__ Wc2, const float* __restrict__ bc2,
                                              const float* __restrict__ Wc3, const float* __restrict__ bc3,
                                              float* __restrict__ out) {
    int g = blockIdx.x;
    int t = threadIdx.x;
    __shared__ float pr[256];
    __shared__ float l1s[16], p1s[16];
    __shared__ float l2s[64], p2s[64];
    pr[t] = pooled[g * 256 + t];
    __syncthreads();
    if (t < 16) {
        float a = bc1[t];
        for (int k = 0; k < 256; ++k) a += pr[k] * Wc1[k * 16 + t];
        l1s[t] = a;
        out[g * 16 + t] = a;
    }
    __syncthreads();
    if (t == 0) {
        float m = -1e30f;
        for (int j = 0; j < 16; ++j) m = fmaxf(m, l1s[j]);
        float s = 0.f;
        for (int j = 0; j < 16; ++j) { float e = expf(l1s[j] - m); p1s[j] = e; s += e; }
        float inv = 1.f / s;
        for (int j = 0; j < 16; ++j) p1s[j] *= inv;
    }
    __syncthreads();
    if (t < 64) {
        float a = bc2[t];
        for (int k = 0; k < 256; ++k) a += pr[k] * Wc2[k * 64 + t];
        for (int k = 0; k < 16; ++k) a += p1s[k] * Wc2[(256 + k) * 64 + t];
        l2s[t] = a;
        out[4096 + g * 64 + t] = a;
    }
    __syncthreads();
    if (t == 0) {
        float m = -1e30f;
        for (int j = 0; j < 64; ++j) m = fmaxf(m, l2s[j]);
        float s = 0.f;
        for (int j = 0; j < 64; ++j) { float e = expf(l2s[j] - m); p2s[j] = e; s += e; }
        float inv = 1.f / s;
        for (int j = 0; j < 64; ++j) p2s[j] *= inv;
    }
    __syncthreads();
    {
        float a = bc3[t];
        for (int k = 0; k < 256; ++k) a += pr[k] * Wc3[k * 256 + t];
        for (int k = 0; k < 64; ++k) a += p2s[k] * Wc3[(256 + k) * 256 + t];
        out[4096 + 16384 + g * 256 + t] = a;
    }
}

// ---------------- launch ----------------

extern "C" void kernel_launch(void* const* d_in, const int* in_sizes, int n_in,
                              void* d_out, int out_size, void* d_ws, size_t ws_size,
                              hipStream_t stream) {
    const float* x    = (const float*)d_in[0];
    const int*   ei   = (const int*)d_in[1];   // [2, E] flat: row0=src, row1=dst
    const int*   batch= (const int*)d_in[2];
    const float* W1 = (const float*)d_in[3];  const float* b1 = (const float*)d_in[4];
    const float* W2 = (const float*)d_in[5];  const float* b2 = (const float*)d_in[6];
    const float* W3 = (const float*)d_in[7];  const float* b3 = (const float*)d_in[8];
    const float* Wc1= (const float*)d_in[9];  const float* bc1= (const float*)d_in[10];
    const float* Wc2= (const float*)d_in[11]; const float* bc2= (const float*)d_in[12];
    const float* Wc3= (const float*)d_in[13]; const float* bc3= (const float*)d_in[14];
    float* out = (float*)d_out;

    const int N = N_NODES, E = N_EDGES, G = N_GRAPHS;

    char* ws = (char*)d_ws;
    size_t off = 0;
    auto alloc = [&](size_t bytes) -> void* {
        void* p = ws + off;
        off = (off + bytes + 255) & ~(size_t)255;
        return p;
    };
    float* bufA   = (float*)alloc((size_t)N * HID * 4);
    float* bufB   = (float*)alloc((size_t)N * HID * 4);
    int*   cnt    = (int*)alloc((size_t)N * 4);
    int*   rp     = (int*)alloc((size_t)N * 4);
    int*   cursor = (int*)alloc((size_t)N * 4);
    float* dinv   = (float*)alloc((size_t)N * 4);
    int*   col    = (int*)alloc((size_t)E * 4);
    float* pooled = (float*)alloc((size_t)G * HID * 4);
    int*   bsums  = (int*)alloc(256 * 4);
    (void)ws_size;

    const int* src = ei;
    const int* dst = ei + E;

    hipMemsetAsync(cnt, 0, (size_t)N * 4, stream);
    count_deg<<<(E + 255) / 256, 256, 0, stream>>>(dst, cnt, E);
    dinv_k<<<(N + 255) / 256, 256, 0, stream>>>(cnt, dinv, N);
    const int NB = (N + 255) / 256;  // 196
    scan1<<<NB, 256, 0, stream>>>(cnt, rp, bsums, N);
    scan2<<<1, 256, 0, stream>>>(bsums, NB);
    scan3<<<NB, 256, 0, stream>>>(rp, cursor, bsums, N);
    fill_csr<<<(E + 255) / 256, 256, 0, stream>>>(src, dst, cursor, col, E);

    dim3 gb(4, (N + 63) / 64);
    gemm_f32<<<gb, 256, 0, stream>>>(x, W1, bufA, N, IN_DIM);
    aggregate<<<N, 256, 0, stream>>>(bufA, bufB, rp, cnt, col, dinv, b1, 1);
    gemm_f32<<<gb, 256, 0, stream>>>(bufB, W2, bufA, N, HID);
    aggregate<<<N, 256, 0, stream>>>(bufA, bufB, rp, cnt, col, dinv, b2, 1);
    gemm_f32<<<gb, 256, 0, stream>>>(bufB, W3, bufA, N, HID);
    aggregate<<<N, 256, 0, stream>>>(bufA, bufB, rp, cnt, col, dinv, b3, 0);

    pool_k<<<G, 256, 0, stream>>>(bufB, batch, pooled, N);
    head_k<<<G, 256, 0, stream>>>(pooled, Wc1, bc1, Wc2, bc2, Wc3, bc3, out);
}

// Round 2
// 707.007 us; speedup vs baseline: 1.4802x; 1.4802x over previous
//
#include <hip/hip_runtime.h>
#include <hip/hip_bf16.h>

#define N_NODES 50000
#define N_EDGES 800000
#define N_GRAPHS 256
#define IN_DIM 300
#define HID 256
#define ROWS_PAD 50048   // N_NODES rounded up to 64

typedef __bf16 bf16x8 __attribute__((ext_vector_type(8)));
typedef short  s16x8  __attribute__((ext_vector_type(8)));
typedef float  f32x4  __attribute__((ext_vector_type(4)));

static __device__ __forceinline__ ushort f2bf(float f) {
    union { float f; uint u; } v; v.f = f;
    uint u = v.u;
    uint r = (u + 0x7fffu + ((u >> 16) & 1u)) >> 16;
    return (ushort)r;
}
static __device__ __forceinline__ float bf2f(ushort b) {
    union { uint u; float f; } v; v.u = ((uint)b) << 16;
    return v.f;
}

// ---------------- CSR build ----------------

__global__ void count_deg(const int* __restrict__ dst, int* __restrict__ cnt, int E) {
    int e = blockIdx.x * 256 + threadIdx.x;
    if (e < E) atomicAdd(&cnt[dst[e]], 1);
}

__global__ void dinv_k(const int* __restrict__ cnt, float* __restrict__ dinv, int n) {
    int i = blockIdx.x * 256 + threadIdx.x;
    if (i < n) dinv[i] = rsqrtf((float)(cnt[i] + 1));  // +1 self-loop
}

__global__ void scan1(const int* __restrict__ cnt, int* __restrict__ rp,
                      int* __restrict__ bsums, int n) {
    __shared__ int s[256];
    int i = blockIdx.x * 256 + threadIdx.x;
    int v = (i < n) ? cnt[i] : 0;
    s[threadIdx.x] = v;
    __syncthreads();
    for (int off = 1; off < 256; off <<= 1) {
        int t = (threadIdx.x >= off) ? s[threadIdx.x - off] : 0;
        __syncthreads();
        s[threadIdx.x] += t;
        __syncthreads();
    }
    if (i < n) rp[i] = s[threadIdx.x] - v;
    if (threadIdx.x == 255) bsums[blockIdx.x] = s[255];
}

__global__ void scan2(int* __restrict__ bsums, int nb) {
    __shared__ int s[256];
    int v = (threadIdx.x < nb) ? bsums[threadIdx.x] : 0;
    s[threadIdx.x] = v;
    __syncthreads();
    for (int off = 1; off < 256; off <<= 1) {
        int t = (threadIdx.x >= off) ? s[threadIdx.x - off] : 0;
        __syncthreads();
        s[threadIdx.x] += t;
        __syncthreads();
    }
    if (threadIdx.x < nb) bsums[threadIdx.x] = s[threadIdx.x] - v;
}

__global__ void scan3(int* __restrict__ rp, int* __restrict__ cursor,
                      const int* __restrict__ bsums, int n) {
    int i = blockIdx.x * 256 + threadIdx.x;
    if (i < n) {
        int v = rp[i] + bsums[blockIdx.x];
        rp[i] = v;
        cursor[i] = v;
    }
}

__global__ void fill_csr(const int* __restrict__ src, const int* __restrict__ dst,
                         int* __restrict__ cursor, int* __restrict__ col, int E) {
    int e = blockIdx.x * 256 + threadIdx.x;
    if (e < E) {
        int d = dst[e];
        int p = atomicAdd(&cursor[d], 1);
        col[p] = src[e];
    }
}

// ---------------- fp32 -> bf16 converts ----------------

// x [N, 300] fp32 -> xb [ROWS_PAD, 320] bf16 (cols 300..319 zero). One block per row.
__global__ __launch_bounds__(320) void convert_x(const float* __restrict__ x,
                                                 ushort* __restrict__ xb) {
    int m = blockIdx.x;
    int k = threadIdx.x;
    xb[(size_t)m * 320 + k] = (k < IN_DIM) ? f2bf(x[(size_t)m * IN_DIM + k]) : (ushort)0;
}

// W [K, 256] fp32 -> Wt [256, Kpad] bf16 (zero-padded k)
__global__ __launch_bounds__(256) void transpose_w(const float* __restrict__ W,
                                                   ushort* __restrict__ Wt, int K, int Kpad) {
    int k = blockIdx.x;   // 0..Kpad-1
    int n = threadIdx.x;  // 0..255
    Wt[(size_t)n * Kpad + k] = (k < K) ? f2bf(W[(size_t)k * 256 + n]) : (ushort)0;
}

// ---------------- bf16 MFMA GEMM: C[M,256] = A[M,KA] @ Bt[256,KA]^T ----------------
// 64x256 tile per block, 256 threads (4 waves), each wave computes 64x64.

template <int KA>
__global__ __launch_bounds__(256) void gemm_bf16(const ushort* __restrict__ A,
                                                 const ushort* __restrict__ Bt,
                                                 ushort* __restrict__ C, int M) {
    __shared__ ushort As[64 * 40];    // stride 40 (pad +8) spreads b128 reads over banks
    __shared__ ushort Bs[256 * 40];

    int t = threadIdx.x;
    int wave = t >> 6, lane = t & 63, quad = lane >> 4, l16 = lane & 15;
    int r0 = blockIdx.x * 64;
    int arow = t >> 2, aseg = t & 3;  // A staging: 64 rows x 4 x 16B

    f32x4 acc[4][4] = {};

    for (int kc = 0; kc < KA; kc += 32) {
        // stage A tile (rows may exceed M-1 but buffer is ROWS_PAD rows)
        *(s16x8*)(As + arow * 40 + aseg * 8) =
            *(const s16x8*)(A + (size_t)(r0 + arow) * KA + kc + aseg * 8);
        // stage B tile (full 256-wide N)
#pragma unroll
        for (int s = 0; s < 4; ++s) {
            *(s16x8*)(Bs + t * 40 + s * 8) =
                *(const s16x8*)(Bt + (size_t)t * KA + kc + s * 8);
        }
        __syncthreads();

        bf16x8 a[4], b[4];
#pragma unroll
        for (int i = 0; i < 4; ++i)
            a[i] = __builtin_bit_cast(bf16x8, *(const s16x8*)(As + (i * 16 + l16) * 40 + quad * 8));
#pragma unroll
        for (int j = 0; j < 4; ++j)
            b[j] = __builtin_bit_cast(bf16x8, *(const s16x8*)(Bs + (wave * 64 + j * 16 + l16) * 40 + quad * 8));
#pragma unroll
        for (int i = 0; i < 4; ++i)
#pragma unroll
            for (int j = 0; j < 4; ++j)
                acc[i][j] = __builtin_amdgcn_mfma_f32_16x16x32_bf16(a[i], b[j], acc[i][j], 0, 0, 0);
        __syncthreads();
    }

    // epilogue: C[row=quad*4+r (within 16-tile)][col=l16]
#pragma unroll
    for (int i = 0; i < 4; ++i) {
        int rowb = r0 + i * 16 + quad * 4;
#pragma unroll
        for (int r = 0; r < 4; ++r) {
            if (rowb + r < M) {
#pragma unroll
                for (int j = 0; j < 4; ++j) {
                    int colv = wave * 64 + j * 16 + l16;
                    C[(size_t)(rowb + r) * 256 + colv] = f2bf(acc[i][j][r]);
                }
            }
        }
    }
}

// ---------------- CSR aggregation (bf16 in/out, fp32 accumulate) ----------------

__global__ __launch_bounds__(256) void aggregate_bf16(const ushort* __restrict__ h,
                                                      ushort* __restrict__ out,
                                                      const int* __restrict__ rp,
                                                      const int* __restrict__ cnt,
                                                      const int* __restrict__ col,
                                                      const float* __restrict__ dinv,
                                                      const float* __restrict__ bias, int relu) {
    int n = blockIdx.x;
    int f = threadIdx.x;
    __shared__ int scol[64];
    __shared__ float sdi[64];
    float dv = dinv[n];
    float acc = dv * bf2f(h[(size_t)n * HID + f]);  // self-loop
    int start = rp[n], c = cnt[n];
    for (int base = 0; base < c; base += 64) {
        if (threadIdx.x < 64) {
            int e = base + threadIdx.x;
            if (e < c) {
                int s0 = col[start + e];
                scol[threadIdx.x] = s0;
                sdi[threadIdx.x] = dinv[s0];
            }
        }
        __syncthreads();
        int m = min(64, c - base);
        float a0 = 0.f, a1 = 0.f, a2 = 0.f, a3 = 0.f;
        int j = 0;
        for (; j + 4 <= m; j += 4) {
            a0 += sdi[j]     * bf2f(h[(size_t)scol[j]     * HID + f]);
            a1 += sdi[j + 1] * bf2f(h[(size_t)scol[j + 1] * HID + f]);
            a2 += sdi[j + 2] * bf2f(h[(size_t)scol[j + 2] * HID + f]);
            a3 += sdi[j + 3] * bf2f(h[(size_t)scol[j + 3] * HID + f]);
        }
        for (; j < m; ++j) a0 += sdi[j] * bf2f(h[(size_t)scol[j] * HID + f]);
        acc += (a0 + a1) + (a2 + a3);
        __syncthreads();
    }
    float r = dv * acc + bias[f];
    if (relu) r = fmaxf(r, 0.f);
    out[(size_t)n * HID + f] = f2bf(r);
}

// ---------------- mean pool per graph (batch sorted) ----------------

__global__ __launch_bounds__(256) void pool_k(const ushort* __restrict__ h,
                                              const int* __restrict__ batch,
                                              float* __restrict__ pooled, int n) {
    int g = blockIdx.x;
    int f = threadIdx.x;
    int lo = 0, hi = n;
    while (lo < hi) { int mid = (lo + hi) >> 1; if (batch[mid] < g) lo = mid + 1; else hi = mid; }
    int start = lo;
    lo = start; hi = n;
    while (lo < hi) { int mid = (lo + hi) >> 1; if (batch[mid] < g + 1) lo = mid + 1; else hi = mid; }
    int end = lo;
    float s = 0.f;
    for (int i = start; i < end; ++i) s += bf2f(h[(size_t)i * HID + f]);
    int c = end - start;
    pooled[g * HID + f] = s / (float)max(c, 1);
}

// ---------------- fused head ----------------

__global__ __launch_bounds__(256) void head_k(const float* __restrict__ pooled,
                                              const float* __restrict__ Wc1, const float* __restrict__ bc1,
                                              const float* __restrict__ Wc2, const float* __restrict__ bc2,
                                              const float* __restrict__ Wc3, const float* __restrict__ bc3,
                                              float* __restrict__ out) {
    int g = blockIdx.x;
    int t = threadIdx.x;
    __shared__ float pr[256];
    __shared__ float l1s[16], p1s[16];
    __shared__ float l2s[64], p2s[64];
    pr[t] = pooled[g * 256 + t];
    __syncthreads();
    if (t < 16) {
        float a = bc1[t];
        for (int k = 0; k < 256; ++k) a += pr[k] * Wc1[k * 16 + t];
        l1s[t] = a;
        out[g * 16 + t] = a;
    }
    __syncthreads();
    if (t == 0) {
        float m = -1e30f;
        for (int j = 0; j < 16; ++j) m = fmaxf(m, l1s[j]);
        float s = 0.f;
        for (int j = 0; j < 16; ++j) { float e = expf(l1s[j] - m); p1s[j] = e; s += e; }
        float inv = 1.f / s;
        for (int j = 0; j < 16; ++j) p1s[j] *= inv;
    }
    __syncthreads();
    if (t < 64) {
        float a = bc2[t];
        for (int k = 0; k < 256; ++k) a += pr[k] * Wc2[k * 64 + t];
        for (int k = 0; k < 16; ++k) a += p1s[k] * Wc2[(256 + k) * 64 + t];
        l2s[t] = a;
        out[4096 + g * 64 + t] = a;
    }
    __syncthreads();
    if (t == 0) {
        float m = -1e30f;
        for (int j = 0; j < 64; ++j) m = fmaxf(m, l2s[j]);
        float s = 0.f;
        for (int j = 0; j < 64; ++j) { float e = expf(l2s[j] - m); p2s[j] = e; s += e; }
        float inv = 1.f / s;
        for (int j = 0; j < 64; ++j) p2s[j] *= inv;
    }
    __syncthreads();
    {
        float a = bc3[t];
        for (int k = 0; k < 256; ++k) a += pr[k] * Wc3[k * 256 + t];
        for (int k = 0; k < 64; ++k) a += p2s[k] * Wc3[(256 + k) * 256 + t];
        out[4096 + 16384 + g * 256 + t] = a;
    }
}

// ---------------- launch ----------------

extern "C" void kernel_launch(void* const* d_in, const int* in_sizes, int n_in,
                              void* d_out, int out_size, void* d_ws, size_t ws_size,
                              hipStream_t stream) {
    const float* x    = (const float*)d_in[0];
    const int*   ei   = (const int*)d_in[1];
    const int*   batch= (const int*)d_in[2];
    const float* W1 = (const float*)d_in[3];  const float* b1 = (const float*)d_in[4];
    const float* W2 = (const float*)d_in[5];  const float* b2 = (const float*)d_in[6];
    const float* W3 = (const float*)d_in[7];  const float* b3 = (const float*)d_in[8];
    const float* Wc1= (const float*)d_in[9];  const float* bc1= (const float*)d_in[10];
    const float* Wc2= (const float*)d_in[11]; const float* bc2= (const float*)d_in[12];
    const float* Wc3= (const float*)d_in[13]; const float* bc3= (const float*)d_in[14];
    float* out = (float*)d_out;

    const int N = N_NODES, E = N_EDGES, G = N_GRAPHS;

    char* ws = (char*)d_ws;
    size_t off = 0;
    auto alloc = [&](size_t bytes) -> void* {
        void* p = ws + off;
        off = (off + bytes + 255) & ~(size_t)255;
        return p;
    };
    ushort* xb   = (ushort*)alloc((size_t)ROWS_PAD * 320 * 2);   // 32.0 MB
    ushort* hbA  = (ushort*)alloc((size_t)ROWS_PAD * HID * 2);   // 25.6 MB
    ushort* hbB  = (ushort*)alloc((size_t)ROWS_PAD * HID * 2);   // 25.6 MB
    ushort* Wt1  = (ushort*)alloc((size_t)256 * 320 * 2);
    ushort* Wt2  = (ushort*)alloc((size_t)256 * 256 * 2);
    ushort* Wt3  = (ushort*)alloc((size_t)256 * 256 * 2);
    int*   cnt    = (int*)alloc((size_t)N * 4);
    int*   rp     = (int*)alloc((size_t)N * 4);
    int*   cursor = (int*)alloc((size_t)N * 4);
    float* dinv   = (float*)alloc((size_t)N * 4);
    int*   col    = (int*)alloc((size_t)E * 4);
    float* pooled = (float*)alloc((size_t)G * HID * 4);
    int*   bsums  = (int*)alloc(256 * 4);
    (void)ws_size;

    const int* src = ei;
    const int* dst = ei + E;

    hipMemsetAsync(cnt, 0, (size_t)N * 4, stream);
    count_deg<<<(E + 255) / 256, 256, 0, stream>>>(dst, cnt, E);
    dinv_k<<<(N + 255) / 256, 256, 0, stream>>>(cnt, dinv, N);
    const int NB = (N + 255) / 256;
    scan1<<<NB, 256, 0, stream>>>(cnt, rp, bsums, N);
    scan2<<<1, 256, 0, stream>>>(bsums, NB);
    scan3<<<NB, 256, 0, stream>>>(rp, cursor, bsums, N);
    fill_csr<<<(E + 255) / 256, 256, 0, stream>>>(src, dst, cursor, col, E);

    convert_x<<<N, 320, 0, stream>>>(x, xb);
    transpose_w<<<320, 256, 0, stream>>>(W1, Wt1, IN_DIM, 320);
    transpose_w<<<256, 256, 0, stream>>>(W2, Wt2, HID, 256);
    transpose_w<<<256, 256, 0, stream>>>(W3, Wt3, HID, 256);

    const int MB = (N + 63) / 64;  // 782
    gemm_bf16<320><<<MB, 256, 0, stream>>>(xb, Wt1, hbA, N);
    aggregate_bf16<<<N, 256, 0, stream>>>(hbA, hbB, rp, cnt, col, dinv, b1, 1);
    gemm_bf16<256><<<MB, 256, 0, stream>>>(hbB, Wt2, hbA, N);
    aggregate_bf16<<<N, 256, 0, stream>>>(hbA, hbB, rp, cnt, col, dinv, b2, 1);
    gemm_bf16<256><<<MB, 256, 0, stream>>>(hbB, Wt3, hbA, N);
    aggregate_bf16<<<N, 256, 0, stream>>>(hbA, hbB, rp, cnt, col, dinv, b3, 0);

    pool_k<<<G, 256, 0, stream>>>(hbB, batch, pooled, N);
    head_k<<<G, 256, 0, stream>>>(pooled, Wc1, bc1, Wc2, bc2, Wc3, bc3, out);
}

// Round 3
// 564.028 us; speedup vs baseline: 1.8555x; 1.2535x over previous
//
#include <hip/hip_runtime.h>
#include <hip/hip_bf16.h>

#define N_NODES 50000
#define N_EDGES 800000
#define N_GRAPHS 256
#define IN_DIM 300
#define HID 256
#define ROWS_PAD 50048   // N_NODES rounded up to 64

typedef __bf16 bf16x8 __attribute__((ext_vector_type(8)));
typedef short  s16x8  __attribute__((ext_vector_type(8)));
typedef short  s16x4  __attribute__((ext_vector_type(4)));
typedef float  f32x4  __attribute__((ext_vector_type(4)));

static __device__ __forceinline__ ushort f2bf(float f) {
    union { float f; uint u; } v; v.f = f;
    uint u = v.u;
    uint r = (u + 0x7fffu + ((u >> 16) & 1u)) >> 16;
    return (ushort)r;
}
static __device__ __forceinline__ float bf2f(ushort b) {
    union { uint u; float f; } v; v.u = ((uint)b) << 16;
    return v.f;
}

// ---------------- CSR build ----------------

__global__ void count_deg(const int* __restrict__ dst, int* __restrict__ cnt, int E) {
    int e = blockIdx.x * 256 + threadIdx.x;
    if (e < E) atomicAdd(&cnt[dst[e]], 1);
}

// exclusive scan step 1 + dinv computation (cnt is final here)
__global__ void scan1(const int* __restrict__ cnt, int* __restrict__ rp,
                      int* __restrict__ bsums, float* __restrict__ dinv, int n) {
    __shared__ int s[256];
    int i = blockIdx.x * 256 + threadIdx.x;
    int v = (i < n) ? cnt[i] : 0;
    if (i < n) dinv[i] = rsqrtf((float)(v + 1));  // +1 self-loop
    s[threadIdx.x] = v;
    __syncthreads();
    for (int off = 1; off < 256; off <<= 1) {
        int t = (threadIdx.x >= off) ? s[threadIdx.x - off] : 0;
        __syncthreads();
        s[threadIdx.x] += t;
        __syncthreads();
    }
    if (i < n) rp[i] = s[threadIdx.x] - v;
    if (threadIdx.x == 255) bsums[blockIdx.x] = s[255];
}

__global__ void scan2(int* __restrict__ bsums, int nb) {
    __shared__ int s[256];
    int v = (threadIdx.x < nb) ? bsums[threadIdx.x] : 0;
    s[threadIdx.x] = v;
    __syncthreads();
    for (int off = 1; off < 256; off <<= 1) {
        int t = (threadIdx.x >= off) ? s[threadIdx.x - off] : 0;
        __syncthreads();
        s[threadIdx.x] += t;
        __syncthreads();
    }
    if (threadIdx.x < nb) bsums[threadIdx.x] = s[threadIdx.x] - v;
}

__global__ void scan3(int* __restrict__ rp, int* __restrict__ cursor,
                      const int* __restrict__ bsums, int n) {
    int i = blockIdx.x * 256 + threadIdx.x;
    if (i < n) {
        int v = rp[i] + bsums[blockIdx.x];
        rp[i] = v;
        cursor[i] = v;
    }
}

__global__ void fill_csr(const int* __restrict__ src, const int* __restrict__ dst,
                         int* __restrict__ cursor, int* __restrict__ col, int E) {
    int e = blockIdx.x * 256 + threadIdx.x;
    if (e < E) {
        int d = dst[e];
        int p = atomicAdd(&cursor[d], 1);
        col[p] = src[e];
    }
}

// ---------------- W [K, 256] fp32 -> Wt [256, Kpad] bf16 (zero-padded k) --------

__global__ __launch_bounds__(256) void transpose_w(const float* __restrict__ W,
                                                   ushort* __restrict__ Wt, int K, int Kpad) {
    int k = blockIdx.x;
    int n = threadIdx.x;
    Wt[(size_t)n * Kpad + k] = (k < K) ? f2bf(W[(size_t)k * 256 + n]) : (ushort)0;
}

// ---------------- bf16 MFMA GEMM: C[M,256] = A[M,K] @ Bt[256,K]^T ----------------
// 64x256 tile per block, 256 threads (4 waves), each wave computes 64x64.
// AF32: A is fp32 [M, KACT] (row stride KACT) converted in-register while staging.

template <int KA, int KACT, bool AF32>
__global__ __launch_bounds__(256) void gemm_bf16(const void* __restrict__ Ap,
                                                 const ushort* __restrict__ Bt,
                                                 ushort* __restrict__ C, int M) {
    __shared__ ushort As[64 * 40];    // stride 40 spreads b128 reads over banks
    __shared__ ushort Bs[256 * 40];

    int t = threadIdx.x;
    int wave = t >> 6, lane = t & 63, quad = lane >> 4, l16 = lane & 15;
    int r0 = blockIdx.x * 64;
    int arow = t >> 2, aseg = t & 3;  // A staging: 64 rows x 4 x (8 bf16)

    f32x4 acc[4][4] = {};

    for (int kc = 0; kc < KA; kc += 32) {
        // stage A tile
        if constexpr (AF32) {
            const float* Af = (const float*)Ap;
            int row = r0 + arow;
            int kb = kc + aseg * 8;
            ushort tmp[8];
            if (row < M && kb + 7 < KACT) {
                f32x4 f0 = *(const f32x4*)(Af + (size_t)row * KACT + kb);
                f32x4 f1 = *(const f32x4*)(Af + (size_t)row * KACT + kb + 4);
#pragma unroll
                for (int i = 0; i < 4; ++i) { tmp[i] = f2bf(f0[i]); tmp[4 + i] = f2bf(f1[i]); }
            } else {
#pragma unroll
                for (int i = 0; i < 8; ++i) {
                    int kk = kb + i;
                    tmp[i] = (row < M && kk < KACT) ? f2bf(Af[(size_t)row * KACT + kk]) : (ushort)0;
                }
            }
            *(s16x8*)(As + arow * 40 + aseg * 8) = *(const s16x8*)tmp;
        } else {
            const ushort* A = (const ushort*)Ap;
            *(s16x8*)(As + arow * 40 + aseg * 8) =
                *(const s16x8*)(A + (size_t)(r0 + arow) * KA + kc + aseg * 8);
        }
        // stage B tile (full 256-wide N)
#pragma unroll
        for (int s = 0; s < 4; ++s) {
            *(s16x8*)(Bs + t * 40 + s * 8) =
                *(const s16x8*)(Bt + (size_t)t * KA + kc + s * 8);
        }
        __syncthreads();

        bf16x8 a[4], b[4];
#pragma unroll
        for (int i = 0; i < 4; ++i)
            a[i] = __builtin_bit_cast(bf16x8, *(const s16x8*)(As + (i * 16 + l16) * 40 + quad * 8));
#pragma unroll
        for (int j = 0; j < 4; ++j)
            b[j] = __builtin_bit_cast(bf16x8, *(const s16x8*)(Bs + (wave * 64 + j * 16 + l16) * 40 + quad * 8));
#pragma unroll
        for (int i = 0; i < 4; ++i)
#pragma unroll
            for (int j = 0; j < 4; ++j)
                acc[i][j] = __builtin_amdgcn_mfma_f32_16x16x32_bf16(a[i], b[j], acc[i][j], 0, 0, 0);
        __syncthreads();
    }

#pragma unroll
    for (int i = 0; i < 4; ++i) {
        int rowb = r0 + i * 16 + quad * 4;
#pragma unroll
        for (int r = 0; r < 4; ++r) {
            if (rowb + r < M) {
#pragma unroll
                for (int j = 0; j < 4; ++j) {
                    int colv = wave * 64 + j * 16 + l16;
                    C[(size_t)(rowb + r) * 256 + colv] = f2bf(acc[i][j][r]);
                }
            }
        }
    }
}

// ---------------- CSR aggregation v2: one wave per node ----------------
// lane covers features [lane*4, lane*4+4); 8 B loads; metadata via scalar loads.

__global__ __launch_bounds__(256) void aggregate_v2(const ushort* __restrict__ h,
                                                    ushort* __restrict__ out,
                                                    const int* __restrict__ rp,
                                                    const int* __restrict__ cnt,
                                                    const int* __restrict__ col,
                                                    const float* __restrict__ dinv,
                                                    const float* __restrict__ bias, int relu) {
    int t = threadIdx.x;
    int wave = __builtin_amdgcn_readfirstlane(t >> 6);  // force SGPR -> scalar metadata loads
    int lane = t & 63;
    int n = blockIdx.x * 4 + wave;           // grid is exactly N/4 blocks
    int start = rp[n];
    int c = cnt[n];
    float dv = dinv[n];
    size_t lo = (size_t)lane * 4;

    float a0 = 0.f, a1 = 0.f, a2 = 0.f, a3 = 0.f;

    int j = 0;
    for (; j + 4 <= c; j += 4) {
        int r0 = col[start + j], r1 = col[start + j + 1];
        int r2 = col[start + j + 2], r3 = col[start + j + 3];
        float w0 = dinv[r0], w1 = dinv[r1], w2 = dinv[r2], w3 = dinv[r3];
        s16x4 v0 = *(const s16x4*)(h + (size_t)r0 * HID + lo);
        s16x4 v1 = *(const s16x4*)(h + (size_t)r1 * HID + lo);
        s16x4 v2 = *(const s16x4*)(h + (size_t)r2 * HID + lo);
        s16x4 v3 = *(const s16x4*)(h + (size_t)r3 * HID + lo);
        a0 += w0 * bf2f((ushort)v0[0]) + w1 * bf2f((ushort)v1[0]) + w2 * bf2f((ushort)v2[0]) + w3 * bf2f((ushort)v3[0]);
        a1 += w0 * bf2f((ushort)v0[1]) + w1 * bf2f((ushort)v1[1]) + w2 * bf2f((ushort)v2[1]) + w3 * bf2f((ushort)v3[1]);
        a2 += w0 * bf2f((ushort)v0[2]) + w1 * bf2f((ushort)v1[2]) + w2 * bf2f((ushort)v2[2]) + w3 * bf2f((ushort)v3[2]);
        a3 += w0 * bf2f((ushort)v0[3]) + w1 * bf2f((ushort)v1[3]) + w2 * bf2f((ushort)v2[3]) + w3 * bf2f((ushort)v3[3]);
    }
    for (; j < c; ++j) {
        int r = col[start + j];
        float w = dinv[r];
        s16x4 v = *(const s16x4*)(h + (size_t)r * HID + lo);
        a0 += w * bf2f((ushort)v[0]);
        a1 += w * bf2f((ushort)v[1]);
        a2 += w * bf2f((ushort)v[2]);
        a3 += w * bf2f((ushort)v[3]);
    }

    // self-loop + norm + bias (+relu), pack and store 8 B per lane
    s16x4 vs = *(const s16x4*)(h + (size_t)n * HID + lo);
    f32x4 bv = *(const f32x4*)(bias + lane * 4);
    ushort o[4];
#pragma unroll
    for (int i = 0; i < 4; ++i) {
        float acc = (i == 0 ? a0 : i == 1 ? a1 : i == 2 ? a2 : a3);
        float r = dv * (acc + dv * bf2f((ushort)vs[i])) + bv[i];
        if (relu) r = fmaxf(r, 0.f);
        o[i] = f2bf(r);
    }
    *(s16x4*)(out + (size_t)n * HID + lo) = *(const s16x4*)o;
}

// ---------------- mean pool per graph (batch sorted) ----------------

__global__ __launch_bounds__(256) void pool_k(const ushort* __restrict__ h,
                                              const int* __restrict__ batch,
                                              float* __restrict__ pooled, int n) {
    int g = blockIdx.x;
    int f = threadIdx.x;
    int lo = 0, hi = n;
    while (lo < hi) { int mid = (lo + hi) >> 1; if (batch[mid] < g) lo = mid + 1; else hi = mid; }
    int start = lo;
    lo = start; hi = n;
    while (lo < hi) { int mid = (lo + hi) >> 1; if (batch[mid] < g + 1) lo = mid + 1; else hi = mid; }
    int end = lo;
    float s = 0.f;
    for (int i = start; i < end; ++i) s += bf2f(h[(size_t)i * HID + f]);
    int c = end - start;
    pooled[g * HID + f] = s / (float)max(c, 1);
}

// ---------------- fused head ----------------

__global__ __launch_bounds__(256) void head_k(const float* __restrict__ pooled,
                                              const float* __restrict__ Wc1, const float* __restrict__ bc1,
                                              const float* __restrict__ Wc2, const float* __restrict__ bc2,
                                              const float* __restrict__ Wc3, const float* __restrict__ bc3,
                                              float* __restrict__ out) {
    int g = blockIdx.x;
    int t = threadIdx.x;
    __shared__ float pr[256];
    __shared__ float l1s[16], p1s[16];
    __shared__ float l2s[64], p2s[64];
    pr[t] = pooled[g * 256 + t];
    __syncthreads();
    if (t < 16) {
        float a = bc1[t];
        for (int k = 0; k < 256; ++k) a += pr[k] * Wc1[k * 16 + t];
        l1s[t] = a;
        out[g * 16 + t] = a;
    }
    __syncthreads();
    if (t == 0) {
        float m = -1e30f;
        for (int j = 0; j < 16; ++j) m = fmaxf(m, l1s[j]);
        float s = 0.f;
        for (int j = 0; j < 16; ++j) { float e = expf(l1s[j] - m); p1s[j] = e; s += e; }
        float inv = 1.f / s;
        for (int j = 0; j < 16; ++j) p1s[j] *= inv;
    }
    __syncthreads();
    if (t < 64) {
        float a = bc2[t];
        for (int k = 0; k < 256; ++k) a += pr[k] * Wc2[k * 64 + t];
        for (int k = 0; k < 16; ++k) a += p1s[k] * Wc2[(256 + k) * 64 + t];
        l2s[t] = a;
        out[4096 + g * 64 + t] = a;
    }
    __syncthreads();
    if (t == 0) {
        float m = -1e30f;
        for (int j = 0; j < 64; ++j) m = fmaxf(m, l2s[j]);
        float s = 0.f;
        for (int j = 0; j < 64; ++j) { float e = expf(l2s[j] - m); p2s[j] = e; s += e; }
        float inv = 1.f / s;
        for (int j = 0; j < 64; ++j) p2s[j] *= inv;
    }
    __syncthreads();
    {
        float a = bc3[t];
        for (int k = 0; k < 256; ++k) a += pr[k] * Wc3[k * 256 + t];
        for (int k = 0; k < 64; ++k) a += p2s[k] * Wc3[(256 + k) * 256 + t];
        out[4096 + 16384 + g * 256 + t] = a;
    }
}

// ---------------- launch ----------------

extern "C" void kernel_launch(void* const* d_in, const int* in_sizes, int n_in,
                              void* d_out, int out_size, void* d_ws, size_t ws_size,
                              hipStream_t stream) {
    const float* x    = (const float*)d_in[0];
    const int*   ei   = (const int*)d_in[1];
    const int*   batch= (const int*)d_in[2];
    const float* W1 = (const float*)d_in[3];  const float* b1 = (const float*)d_in[4];
    const float* W2 = (const float*)d_in[5];  const float* b2 = (const float*)d_in[6];
    const float* W3 = (const float*)d_in[7];  const float* b3 = (const float*)d_in[8];
    const float* Wc1= (const float*)d_in[9];  const float* bc1= (const float*)d_in[10];
    const float* Wc2= (const float*)d_in[11]; const float* bc2= (const float*)d_in[12];
    const float* Wc3= (const float*)d_in[13]; const float* bc3= (const float*)d_in[14];
    float* out = (float*)d_out;

    const int N = N_NODES, E = N_EDGES, G = N_GRAPHS;

    char* ws = (char*)d_ws;
    size_t off = 0;
    auto alloc = [&](size_t bytes) -> void* {
        void* p = ws + off;
        off = (off + bytes + 255) & ~(size_t)255;
        return p;
    };
    ushort* hbA  = (ushort*)alloc((size_t)ROWS_PAD * HID * 2);   // 25.6 MB
    ushort* hbB  = (ushort*)alloc((size_t)ROWS_PAD * HID * 2);   // 25.6 MB
    ushort* Wt1  = (ushort*)alloc((size_t)256 * 320 * 2);
    ushort* Wt2  = (ushort*)alloc((size_t)256 * 256 * 2);
    ushort* Wt3  = (ushort*)alloc((size_t)256 * 256 * 2);
    int*   cnt    = (int*)alloc((size_t)N * 4);
    int*   rp     = (int*)alloc((size_t)N * 4);
    int*   cursor = (int*)alloc((size_t)N * 4);
    float* dinv   = (float*)alloc((size_t)N * 4);
    int*   col    = (int*)alloc((size_t)E * 4);
    float* pooled = (float*)alloc((size_t)G * HID * 4);
    int*   bsums  = (int*)alloc(256 * 4);
    (void)ws_size;

    const int* src = ei;
    const int* dst = ei + E;

    hipMemsetAsync(cnt, 0, (size_t)N * 4, stream);
    count_deg<<<(E + 255) / 256, 256, 0, stream>>>(dst, cnt, E);
    const int NB = (N + 255) / 256;
    scan1<<<NB, 256, 0, stream>>>(cnt, rp, bsums, dinv, N);
    scan2<<<1, 256, 0, stream>>>(bsums, NB);
    scan3<<<NB, 256, 0, stream>>>(rp, cursor, bsums, N);
    fill_csr<<<(E + 255) / 256, 256, 0, stream>>>(src, dst, cursor, col, E);

    transpose_w<<<320, 256, 0, stream>>>(W1, Wt1, IN_DIM, 320);
    transpose_w<<<256, 256, 0, stream>>>(W2, Wt2, HID, 256);
    transpose_w<<<256, 256, 0, stream>>>(W3, Wt3, HID, 256);

    const int MB = (N + 63) / 64;  // 782
    gemm_bf16<320, IN_DIM, true><<<MB, 256, 0, stream>>>(x, Wt1, hbA, N);
    aggregate_v2<<<N / 4, 256, 0, stream>>>(hbA, hbB, rp, cnt, col, dinv, b1, 1);
    gemm_bf16<256, 256, false><<<MB, 256, 0, stream>>>(hbB, Wt2, hbA, N);
    aggregate_v2<<<N / 4, 256, 0, stream>>>(hbA, hbB, rp, cnt, col, dinv, b2, 1);
    gemm_bf16<256, 256, false><<<MB, 256, 0, stream>>>(hbB, Wt3, hbA, N);
    aggregate_v2<<<N / 4, 256, 0, stream>>>(hbA, hbB, rp, cnt, col, dinv, b3, 0);

    pool_k<<<G, 256, 0, stream>>>(hbB, batch, pooled, N);
    head_k<<<G, 256, 0, stream>>>(pooled, Wc1, bc1, Wc2, bc2, Wc3, bc3, out);
}

// Round 4
// 513.133 us; speedup vs baseline: 2.0395x; 1.0992x over previous
//
#include <hip/hip_runtime.h>
#include <hip/hip_bf16.h>

#define N_NODES 50000
#define N_EDGES 800000
#define N_GRAPHS 256
#define IN_DIM 300
#define HID 256
#define ROWS_PAD 50048   // N_NODES rounded up to 64

typedef __bf16 bf16x8 __attribute__((ext_vector_type(8)));
typedef short  s16x8  __attribute__((ext_vector_type(8)));
typedef short  s16x4  __attribute__((ext_vector_type(4)));
typedef float  f32x4  __attribute__((ext_vector_type(4)));

static __device__ __forceinline__ ushort f2bf(float f) {
    union { float f; uint u; } v; v.f = f;
    uint u = v.u;
    uint r = (u + 0x7fffu + ((u >> 16) & 1u)) >> 16;
    return (ushort)r;
}
static __device__ __forceinline__ float bf2f(ushort b) {
    union { uint u; float f; } v; v.u = ((uint)b) << 16;
    return v.f;
}

// ---------------- CSR build ----------------

__global__ void count_deg(const int* __restrict__ dst, int* __restrict__ cnt, int E) {
    int e = blockIdx.x * 256 + threadIdx.x;
    if (e < E) atomicAdd(&cnt[dst[e]], 1);
}

// exclusive scan step 1 + dinv computation (cnt is final here)
__global__ void scan1(const int* __restrict__ cnt, int* __restrict__ rp,
                      int* __restrict__ bsums, float* __restrict__ dinv, int n) {
    __shared__ int s[256];
    int i = blockIdx.x * 256 + threadIdx.x;
    int v = (i < n) ? cnt[i] : 0;
    if (i < n) dinv[i] = rsqrtf((float)(v + 1));  // +1 self-loop
    s[threadIdx.x] = v;
    __syncthreads();
    for (int off = 1; off < 256; off <<= 1) {
        int t = (threadIdx.x >= off) ? s[threadIdx.x - off] : 0;
        __syncthreads();
        s[threadIdx.x] += t;
        __syncthreads();
    }
    if (i < n) rp[i] = s[threadIdx.x] - v;
    if (threadIdx.x == 255) bsums[blockIdx.x] = s[255];
}

__global__ void scan2(int* __restrict__ bsums, int nb) {
    __shared__ int s[256];
    int v = (threadIdx.x < nb) ? bsums[threadIdx.x] : 0;
    s[threadIdx.x] = v;
    __syncthreads();
    for (int off = 1; off < 256; off <<= 1) {
        int t = (threadIdx.x >= off) ? s[threadIdx.x - off] : 0;
        __syncthreads();
        s[threadIdx.x] += t;
        __syncthreads();
    }
    if (threadIdx.x < nb) bsums[threadIdx.x] = s[threadIdx.x] - v;
}

__global__ void scan3(int* __restrict__ rp, int* __restrict__ cursor,
                      const int* __restrict__ bsums, int n) {
    int i = blockIdx.x * 256 + threadIdx.x;
    if (i < n) {
        int v = rp[i] + bsums[blockIdx.x];
        rp[i] = v;
        cursor[i] = v;
    }
}

__global__ void fill_csr(const int* __restrict__ src, const int* __restrict__ dst,
                         int* __restrict__ cursor, int* __restrict__ col, int E) {
    int e = blockIdx.x * 256 + threadIdx.x;
    if (e < E) {
        int d = dst[e];
        int p = atomicAdd(&cursor[d], 1);
        col[p] = src[e];
    }
}

// ---------------- W [K, 256] fp32 -> Wt [256, Kpad] bf16 (zero-padded k) --------

__global__ __launch_bounds__(256) void transpose_w(const float* __restrict__ W,
                                                   ushort* __restrict__ Wt, int K, int Kpad) {
    int k = blockIdx.x;
    int n = threadIdx.x;
    Wt[(size_t)n * Kpad + k] = (k < K) ? f2bf(W[(size_t)k * 256 + n]) : (ushort)0;
}

// ---------------- bf16 MFMA GEMM: C[M,256] = A[M,K] @ Bt[256,K]^T ----------------

template <int KA, int KACT, bool AF32>
__global__ __launch_bounds__(256) void gemm_bf16(const void* __restrict__ Ap,
                                                 const ushort* __restrict__ Bt,
                                                 ushort* __restrict__ C, int M) {
    __shared__ ushort As[64 * 40];
    __shared__ ushort Bs[256 * 40];

    int t = threadIdx.x;
    int wave = t >> 6, lane = t & 63, quad = lane >> 4, l16 = lane & 15;
    int r0 = blockIdx.x * 64;
    int arow = t >> 2, aseg = t & 3;

    f32x4 acc[4][4] = {};

    for (int kc = 0; kc < KA; kc += 32) {
        if constexpr (AF32) {
            const float* Af = (const float*)Ap;
            int row = r0 + arow;
            int kb = kc + aseg * 8;
            ushort tmp[8];
            if (row < M && kb + 7 < KACT) {
                f32x4 f0 = *(const f32x4*)(Af + (size_t)row * KACT + kb);
                f32x4 f1 = *(const f32x4*)(Af + (size_t)row * KACT + kb + 4);
#pragma unroll
                for (int i = 0; i < 4; ++i) { tmp[i] = f2bf(f0[i]); tmp[4 + i] = f2bf(f1[i]); }
            } else {
#pragma unroll
                for (int i = 0; i < 8; ++i) {
                    int kk = kb + i;
                    tmp[i] = (row < M && kk < KACT) ? f2bf(Af[(size_t)row * KACT + kk]) : (ushort)0;
                }
            }
            *(s16x8*)(As + arow * 40 + aseg * 8) = *(const s16x8*)tmp;
        } else {
            const ushort* A = (const ushort*)Ap;
            *(s16x8*)(As + arow * 40 + aseg * 8) =
                *(const s16x8*)(A + (size_t)(r0 + arow) * KA + kc + aseg * 8);
        }
#pragma unroll
        for (int s = 0; s < 4; ++s) {
            *(s16x8*)(Bs + t * 40 + s * 8) =
                *(const s16x8*)(Bt + (size_t)t * KA + kc + s * 8);
        }
        __syncthreads();

        bf16x8 a[4], b[4];
#pragma unroll
        for (int i = 0; i < 4; ++i)
            a[i] = __builtin_bit_cast(bf16x8, *(const s16x8*)(As + (i * 16 + l16) * 40 + quad * 8));
#pragma unroll
        for (int j = 0; j < 4; ++j)
            b[j] = __builtin_bit_cast(bf16x8, *(const s16x8*)(Bs + (wave * 64 + j * 16 + l16) * 40 + quad * 8));
#pragma unroll
        for (int i = 0; i < 4; ++i)
#pragma unroll
            for (int j = 0; j < 4; ++j)
                acc[i][j] = __builtin_amdgcn_mfma_f32_16x16x32_bf16(a[i], b[j], acc[i][j], 0, 0, 0);
        __syncthreads();
    }

#pragma unroll
    for (int i = 0; i < 4; ++i) {
        int rowb = r0 + i * 16 + quad * 4;
#pragma unroll
        for (int r = 0; r < 4; ++r) {
            if (rowb + r < M) {
#pragma unroll
                for (int j = 0; j < 4; ++j) {
                    int colv = wave * 64 + j * 16 + l16;
                    C[(size_t)(rowb + r) * 256 + colv] = f2bf(acc[i][j][r]);
                }
            }
        }
    }
}

// ---------------- CSR aggregation: one wave per node ----------------

__global__ __launch_bounds__(256) void aggregate_v2(const ushort* __restrict__ h,
                                                    ushort* __restrict__ out,
                                                    const int* __restrict__ rp,
                                                    const int* __restrict__ cnt,
                                                    const int* __restrict__ col,
                                                    const float* __restrict__ dinv,
                                                    const float* __restrict__ bias, int relu) {
    int t = threadIdx.x;
    int wave = __builtin_amdgcn_readfirstlane(t >> 6);
    int lane = t & 63;
    int n = blockIdx.x * 4 + wave;
    int start = rp[n];
    int c = cnt[n];
    float dv = dinv[n];
    size_t lo = (size_t)lane * 4;

    float a0 = 0.f, a1 = 0.f, a2 = 0.f, a3 = 0.f;

    int j = 0;
    for (; j + 4 <= c; j += 4) {
        int r0 = col[start + j], r1 = col[start + j + 1];
        int r2 = col[start + j + 2], r3 = col[start + j + 3];
        float w0 = dinv[r0], w1 = dinv[r1], w2 = dinv[r2], w3 = dinv[r3];
        s16x4 v0 = *(const s16x4*)(h + (size_t)r0 * HID + lo);
        s16x4 v1 = *(const s16x4*)(h + (size_t)r1 * HID + lo);
        s16x4 v2 = *(const s16x4*)(h + (size_t)r2 * HID + lo);
        s16x4 v3 = *(const s16x4*)(h + (size_t)r3 * HID + lo);
        a0 += w0 * bf2f((ushort)v0[0]) + w1 * bf2f((ushort)v1[0]) + w2 * bf2f((ushort)v2[0]) + w3 * bf2f((ushort)v3[0]);
        a1 += w0 * bf2f((ushort)v0[1]) + w1 * bf2f((ushort)v1[1]) + w2 * bf2f((ushort)v2[1]) + w3 * bf2f((ushort)v3[1]);
        a2 += w0 * bf2f((ushort)v0[2]) + w1 * bf2f((ushort)v1[2]) + w2 * bf2f((ushort)v2[2]) + w3 * bf2f((ushort)v3[2]);
        a3 += w0 * bf2f((ushort)v0[3]) + w1 * bf2f((ushort)v1[3]) + w2 * bf2f((ushort)v2[3]) + w3 * bf2f((ushort)v3[3]);
    }
    for (; j < c; ++j) {
        int r = col[start + j];
        float w = dinv[r];
        s16x4 v = *(const s16x4*)(h + (size_t)r * HID + lo);
        a0 += w * bf2f((ushort)v[0]);
        a1 += w * bf2f((ushort)v[1]);
        a2 += w * bf2f((ushort)v[2]);
        a3 += w * bf2f((ushort)v[3]);
    }

    s16x4 vs = *(const s16x4*)(h + (size_t)n * HID + lo);
    f32x4 bv = *(const f32x4*)(bias + lane * 4);
    ushort o[4];
#pragma unroll
    for (int i = 0; i < 4; ++i) {
        float acc = (i == 0 ? a0 : i == 1 ? a1 : i == 2 ? a2 : a3);
        float r = dv * (acc + dv * bf2f((ushort)vs[i])) + bv[i];
        if (relu) r = fmaxf(r, 0.f);
        o[i] = f2bf(r);
    }
    *(s16x4*)(out + (size_t)n * HID + lo) = *(const s16x4*)o;
}

// ---------------- pool: segmented sum over sorted batch ----------------
// block b covers rows [b*64, b*64+64); thread t owns feature t; flush on
// graph-id change via atomicAdd into psum (zeroed beforehand).

__global__ __launch_bounds__(256) void pool_sum(const ushort* __restrict__ h,
                                                const int* __restrict__ batch,
                                                float* __restrict__ psum, int n) {
    int f = threadIdx.x;
    int r0 = blockIdx.x * 64;
    int rend = min(r0 + 64, n);
    if (r0 >= n) return;
    int g = batch[r0];
    float acc = 0.f;
    for (int r = r0; r < rend; ++r) {
        int gr = batch[r];
        if (gr != g) {
            atomicAdd(&psum[g * HID + f], acc);
            acc = 0.f;
            g = gr;
        }
        acc += bf2f(h[(size_t)r * HID + f]);
    }
    atomicAdd(&psum[g * HID + f], acc);
}

// ---------------- fused head (divides psum by graph size) ----------------

__global__ __launch_bounds__(256) void head_k(const float* __restrict__ psum,
                                              const int* __restrict__ batch, int n,
                                              const float* __restrict__ Wc1, const float* __restrict__ bc1,
                                              const float* __restrict__ Wc2, const float* __restrict__ bc2,
                                              const float* __restrict__ Wc3, const float* __restrict__ bc3,
                                              float* __restrict__ out) {
    int g = blockIdx.x;
    int t = threadIdx.x;
    __shared__ float pr[256];
    __shared__ float l1s[16], p1s[16];
    __shared__ float l2s[64], p2s[64];
    // node count for graph g (batch sorted)
    int lo = 0, hi = n;
    while (lo < hi) { int mid = (lo + hi) >> 1; if (batch[mid] < g) lo = mid + 1; else hi = mid; }
    int start = lo;
    lo = start; hi = n;
    while (lo < hi) { int mid = (lo + hi) >> 1; if (batch[mid] < g + 1) lo = mid + 1; else hi = mid; }
    int c = lo - start;
    float inv_c = 1.f / (float)max(c, 1);
    pr[t] = psum[g * 256 + t] * inv_c;
    __syncthreads();
    if (t < 16) {
        float a = bc1[t];
        for (int k = 0; k < 256; ++k) a += pr[k] * Wc1[k * 16 + t];
        l1s[t] = a;
        out[g * 16 + t] = a;
    }
    __syncthreads();
    if (t == 0) {
        float m = -1e30f;
        for (int j = 0; j < 16; ++j) m = fmaxf(m, l1s[j]);
        float s = 0.f;
        for (int j = 0; j < 16; ++j) { float e = expf(l1s[j] - m); p1s[j] = e; s += e; }
        float inv = 1.f / s;
        for (int j = 0; j < 16; ++j) p1s[j] *= inv;
    }
    __syncthreads();
    if (t < 64) {
        float a = bc2[t];
        for (int k = 0; k < 256; ++k) a += pr[k] * Wc2[k * 64 + t];
        for (int k = 0; k < 16; ++k) a += p1s[k] * Wc2[(256 + k) * 64 + t];
        l2s[t] = a;
        out[4096 + g * 64 + t] = a;
    }
    __syncthreads();
    if (t == 0) {
        float m = -1e30f;
        for (int j = 0; j < 64; ++j) m = fmaxf(m, l2s[j]);
        float s = 0.f;
        for (int j = 0; j < 64; ++j) { float e = expf(l2s[j] - m); p2s[j] = e; s += e; }
        float inv = 1.f / s;
        for (int j = 0; j < 64; ++j) p2s[j] *= inv;
    }
    __syncthreads();
    {
        float a = bc3[t];
        for (int k = 0; k < 256; ++k) a += pr[k] * Wc3[k * 256 + t];
        for (int k = 0; k < 64; ++k) a += p2s[k] * Wc3[(256 + k) * 256 + t];
        out[4096 + 16384 + g * 256 + t] = a;
    }
}

// ---------------- launch ----------------

extern "C" void kernel_launch(void* const* d_in, const int* in_sizes, int n_in,
                              void* d_out, int out_size, void* d_ws, size_t ws_size,
                              hipStream_t stream) {
    const float* x    = (const float*)d_in[0];
    const int*   ei   = (const int*)d_in[1];
    const int*   batch= (const int*)d_in[2];
    const float* W1 = (const float*)d_in[3];  const float* b1 = (const float*)d_in[4];
    const float* W2 = (const float*)d_in[5];  const float* b2 = (const float*)d_in[6];
    const float* W3 = (const float*)d_in[7];  const float* b3 = (const float*)d_in[8];
    const float* Wc1= (const float*)d_in[9];  const float* bc1= (const float*)d_in[10];
    const float* Wc2= (const float*)d_in[11]; const float* bc2= (const float*)d_in[12];
    const float* Wc3= (const float*)d_in[13]; const float* bc3= (const float*)d_in[14];
    float* out = (float*)d_out;

    const int N = N_NODES, E = N_EDGES, G = N_GRAPHS;

    char* ws = (char*)d_ws;
    size_t off = 0;
    auto alloc = [&](size_t bytes) -> void* {
        void* p = ws + off;
        off = (off + bytes + 255) & ~(size_t)255;
        return p;
    };
    ushort* hbA  = (ushort*)alloc((size_t)ROWS_PAD * HID * 2);
    ushort* hbB  = (ushort*)alloc((size_t)ROWS_PAD * HID * 2);
    ushort* Wt1  = (ushort*)alloc((size_t)256 * 320 * 2);
    ushort* Wt2  = (ushort*)alloc((size_t)256 * 256 * 2);
    ushort* Wt3  = (ushort*)alloc((size_t)256 * 256 * 2);
    int*   cnt    = (int*)alloc((size_t)N * 4);
    int*   rp     = (int*)alloc((size_t)N * 4);
    int*   cursor = (int*)alloc((size_t)N * 4);
    float* dinv   = (float*)alloc((size_t)N * 4);
    int*   col    = (int*)alloc((size_t)E * 4);
    float* psum   = (float*)alloc((size_t)G * HID * 4);
    int*   bsums  = (int*)alloc(256 * 4);
    (void)ws_size;

    const int* src = ei;
    const int* dst = ei + E;

    hipMemsetAsync(cnt, 0, (size_t)N * 4, stream);
    hipMemsetAsync(psum, 0, (size_t)G * HID * 4, stream);
    count_deg<<<(E + 255) / 256, 256, 0, stream>>>(dst, cnt, E);
    const int NB = (N + 255) / 256;
    scan1<<<NB, 256, 0, stream>>>(cnt, rp, bsums, dinv, N);
    scan2<<<1, 256, 0, stream>>>(bsums, NB);
    scan3<<<NB, 256, 0, stream>>>(rp, cursor, bsums, N);
    fill_csr<<<(E + 255) / 256, 256, 0, stream>>>(src, dst, cursor, col, E);

    transpose_w<<<320, 256, 0, stream>>>(W1, Wt1, IN_DIM, 320);
    transpose_w<<<256, 256, 0, stream>>>(W2, Wt2, HID, 256);
    transpose_w<<<256, 256, 0, stream>>>(W3, Wt3, HID, 256);

    const int MB = (N + 63) / 64;  // 782
    gemm_bf16<320, IN_DIM, true><<<MB, 256, 0, stream>>>(x, Wt1, hbA, N);
    aggregate_v2<<<N / 4, 256, 0, stream>>>(hbA, hbB, rp, cnt, col, dinv, b1, 1);
    gemm_bf16<256, 256, false><<<MB, 256, 0, stream>>>(hbB, Wt2, hbA, N);
    aggregate_v2<<<N / 4, 256, 0, stream>>>(hbA, hbB, rp, cnt, col, dinv, b2, 1);
    gemm_bf16<256, 256, false><<<MB, 256, 0, stream>>>(hbB, Wt3, hbA, N);
    aggregate_v2<<<N / 4, 256, 0, stream>>>(hbA, hbB, rp, cnt, col, dinv, b3, 0);

    pool_sum<<<MB, 256, 0, stream>>>(hbB, batch, psum, N);
    head_k<<<G, 256, 0, stream>>>(psum, batch, N, Wc1, bc1, Wc2, bc2, Wc3, bc3, out);
}

// Round 5
// 443.015 us; speedup vs baseline: 2.3623x; 1.1583x over previous
//
#include <hip/hip_runtime.h>
#include <hip/hip_bf16.h>

#define N_NODES 50000
#define N_EDGES 800000
#define N_GRAPHS 256
#define IN_DIM 300
#define HID 256
#define ROWS_PAD 50048   // N_NODES rounded up to 64

typedef __bf16 bf16x8 __attribute__((ext_vector_type(8)));
typedef short  s16x8  __attribute__((ext_vector_type(8)));
typedef short  s16x4  __attribute__((ext_vector_type(4)));
typedef float  f32x4  __attribute__((ext_vector_type(4)));
typedef float  f32x2  __attribute__((ext_vector_type(2)));

static __device__ __forceinline__ ushort f2bf(float f) {
    union { float f; uint u; } v; v.f = f;
    uint u = v.u;
    uint r = (u + 0x7fffu + ((u >> 16) & 1u)) >> 16;
    return (ushort)r;
}
static __device__ __forceinline__ float bf2f(ushort b) {
    union { uint u; float f; } v; v.u = ((uint)b) << 16;
    return v.f;
}
static __device__ __forceinline__ unsigned char f2fp8(float f) {
    int pk = __builtin_amdgcn_cvt_pk_fp8_f32(f, f, 0, 0);  // OCP e4m3 on gfx950
    return (unsigned char)(pk & 0xff);
}

// ---------------- CSR build ----------------

__global__ void count_deg(const int* __restrict__ dst, int* __restrict__ cnt, int E) {
    int e = blockIdx.x * 256 + threadIdx.x;
    if (e < E) atomicAdd(&cnt[dst[e]], 1);
}

__global__ void scan1(const int* __restrict__ cnt, int* __restrict__ rp,
                      int* __restrict__ bsums, float* __restrict__ dinv, int n) {
    __shared__ int s[256];
    int i = blockIdx.x * 256 + threadIdx.x;
    int v = (i < n) ? cnt[i] : 0;
    if (i < n) dinv[i] = rsqrtf((float)(v + 1));  // +1 self-loop
    s[threadIdx.x] = v;
    __syncthreads();
    for (int off = 1; off < 256; off <<= 1) {
        int t = (threadIdx.x >= off) ? s[threadIdx.x - off] : 0;
        __syncthreads();
        s[threadIdx.x] += t;
        __syncthreads();
    }
    if (i < n) rp[i] = s[threadIdx.x] - v;
    if (threadIdx.x == 255) bsums[blockIdx.x] = s[255];
}

__global__ void scan2(int* __restrict__ bsums, int nb) {
    __shared__ int s[256];
    int v = (threadIdx.x < nb) ? bsums[threadIdx.x] : 0;
    s[threadIdx.x] = v;
    __syncthreads();
    for (int off = 1; off < 256; off <<= 1) {
        int t = (threadIdx.x >= off) ? s[threadIdx.x - off] : 0;
        __syncthreads();
        s[threadIdx.x] += t;
        __syncthreads();
    }
    if (threadIdx.x < nb) bsums[threadIdx.x] = s[threadIdx.x] - v;
}

__global__ void scan3(int* __restrict__ rp, int* __restrict__ cursor,
                      const int* __restrict__ bsums, int n) {
    int i = blockIdx.x * 256 + threadIdx.x;
    if (i < n) {
        int v = rp[i] + bsums[blockIdx.x];
        rp[i] = v;
        cursor[i] = v;
    }
}

__global__ void fill_csr(const int* __restrict__ src, const int* __restrict__ dst,
                         int* __restrict__ cursor, int* __restrict__ col, int E) {
    int e = blockIdx.x * 256 + threadIdx.x;
    if (e < E) {
        int d = dst[e];
        int p = atomicAdd(&cursor[d], 1);
        col[p] = src[e];
    }
}

// ---------------- all 3 weight transposes in one dispatch ----------------
// blocks [0,320): W1 k-slice; [320,576): W2; [576,832): W3.

__global__ __launch_bounds__(256) void transpose_w3(const float* __restrict__ W1,
                                                    const float* __restrict__ W2,
                                                    const float* __restrict__ W3,
                                                    ushort* __restrict__ Wt1,
                                                    ushort* __restrict__ Wt2,
                                                    ushort* __restrict__ Wt3) {
    int b = blockIdx.x;
    int n = threadIdx.x;
    if (b < 320) {
        int k = b;
        Wt1[(size_t)n * 320 + k] = (k < IN_DIM) ? f2bf(W1[(size_t)k * 256 + n]) : (ushort)0;
    } else if (b < 576) {
        int k = b - 320;
        Wt2[(size_t)n * 256 + k] = f2bf(W2[(size_t)k * 256 + n]);
    } else {
        int k = b - 576;
        Wt3[(size_t)n * 256 + k] = f2bf(W3[(size_t)k * 256 + n]);
    }
}

// ---------------- bf16 MFMA GEMM: Z[M,256] = A[M,K] @ Bt[256,K]^T, Z in fp8 ----

template <int KA, int KACT, bool AF32>
__global__ __launch_bounds__(256) void gemm_bf16(const void* __restrict__ Ap,
                                                 const ushort* __restrict__ Bt,
                                                 unsigned char* __restrict__ C, int M) {
    __shared__ ushort As[64 * 40];
    __shared__ ushort Bs[256 * 40];

    int t = threadIdx.x;
    int wave = t >> 6, lane = t & 63, quad = lane >> 4, l16 = lane & 15;
    int r0 = blockIdx.x * 64;
    int arow = t >> 2, aseg = t & 3;

    f32x4 acc[4][4] = {};

    for (int kc = 0; kc < KA; kc += 32) {
        if constexpr (AF32) {
            const float* Af = (const float*)Ap;
            int row = r0 + arow;
            int kb = kc + aseg * 8;
            ushort tmp[8];
            if (row < M && kb + 7 < KACT) {
                f32x4 f0 = *(const f32x4*)(Af + (size_t)row * KACT + kb);
                f32x4 f1 = *(const f32x4*)(Af + (size_t)row * KACT + kb + 4);
#pragma unroll
                for (int i = 0; i < 4; ++i) { tmp[i] = f2bf(f0[i]); tmp[4 + i] = f2bf(f1[i]); }
            } else {
#pragma unroll
                for (int i = 0; i < 8; ++i) {
                    int kk = kb + i;
                    tmp[i] = (row < M && kk < KACT) ? f2bf(Af[(size_t)row * KACT + kk]) : (ushort)0;
                }
            }
            *(s16x8*)(As + arow * 40 + aseg * 8) = *(const s16x8*)tmp;
        } else {
            const ushort* A = (const ushort*)Ap;
            *(s16x8*)(As + arow * 40 + aseg * 8) =
                *(const s16x8*)(A + (size_t)(r0 + arow) * KA + kc + aseg * 8);
        }
#pragma unroll
        for (int s = 0; s < 4; ++s) {
            *(s16x8*)(Bs + t * 40 + s * 8) =
                *(const s16x8*)(Bt + (size_t)t * KA + kc + s * 8);
        }
        __syncthreads();

        bf16x8 a[4], b[4];
#pragma unroll
        for (int i = 0; i < 4; ++i)
            a[i] = __builtin_bit_cast(bf16x8, *(const s16x8*)(As + (i * 16 + l16) * 40 + quad * 8));
#pragma unroll
        for (int j = 0; j < 4; ++j)
            b[j] = __builtin_bit_cast(bf16x8, *(const s16x8*)(Bs + (wave * 64 + j * 16 + l16) * 40 + quad * 8));
#pragma unroll
        for (int i = 0; i < 4; ++i)
#pragma unroll
            for (int j = 0; j < 4; ++j)
                acc[i][j] = __builtin_amdgcn_mfma_f32_16x16x32_bf16(a[i], b[j], acc[i][j], 0, 0, 0);
        __syncthreads();
    }

#pragma unroll
    for (int i = 0; i < 4; ++i) {
        int rowb = r0 + i * 16 + quad * 4;
#pragma unroll
        for (int r = 0; r < 4; ++r) {
            if (rowb + r < M) {
#pragma unroll
                for (int j = 0; j < 4; ++j) {
                    int colv = wave * 64 + j * 16 + l16;
                    C[(size_t)(rowb + r) * 256 + colv] = f2fp8(acc[i][j][r]);
                }
            }
        }
    }
}

// ---------------- CSR aggregation: one wave per node, fp8 gather ----------------
// z rows are 256 fp8 = 64 dwords; lane loads dword -> 4 features.

__global__ __launch_bounds__(256) void aggregate_fp8(const unsigned char* __restrict__ z,
                                                     ushort* __restrict__ out,
                                                     const int* __restrict__ rp,
                                                     const int* __restrict__ cnt,
                                                     const int* __restrict__ col,
                                                     const float* __restrict__ dinv,
                                                     const float* __restrict__ bias, int relu) {
    const uint* zu = (const uint*)z;
    int t = threadIdx.x;
    int wave = __builtin_amdgcn_readfirstlane(t >> 6);
    int lane = t & 63;
    int n = blockIdx.x * 4 + wave;
    int start = rp[n];
    int c = cnt[n];
    float dv = dinv[n];

    float a0 = 0.f, a1 = 0.f, a2 = 0.f, a3 = 0.f;

    int j = 0;
    for (; j + 4 <= c; j += 4) {
        int r0 = col[start + j], r1 = col[start + j + 1];
        int r2 = col[start + j + 2], r3 = col[start + j + 3];
        float w0 = dinv[r0], w1 = dinv[r1], w2 = dinv[r2], w3 = dinv[r3];
        uint v0 = zu[(size_t)r0 * 64 + lane];
        uint v1 = zu[(size_t)r1 * 64 + lane];
        uint v2 = zu[(size_t)r2 * 64 + lane];
        uint v3 = zu[(size_t)r3 * 64 + lane];
        f32x2 p, q;
        p = __builtin_amdgcn_cvt_pk_f32_fp8(v0, 0); q = __builtin_amdgcn_cvt_pk_f32_fp8(v0, 1);
        a0 += w0 * p[0]; a1 += w0 * p[1]; a2 += w0 * q[0]; a3 += w0 * q[1];
        p = __builtin_amdgcn_cvt_pk_f32_fp8(v1, 0); q = __builtin_amdgcn_cvt_pk_f32_fp8(v1, 1);
        a0 += w1 * p[0]; a1 += w1 * p[1]; a2 += w1 * q[0]; a3 += w1 * q[1];
        p = __builtin_amdgcn_cvt_pk_f32_fp8(v2, 0); q = __builtin_amdgcn_cvt_pk_f32_fp8(v2, 1);
        a0 += w2 * p[0]; a1 += w2 * p[1]; a2 += w2 * q[0]; a3 += w2 * q[1];
        p = __builtin_amdgcn_cvt_pk_f32_fp8(v3, 0); q = __builtin_amdgcn_cvt_pk_f32_fp8(v3, 1);
        a0 += w3 * p[0]; a1 += w3 * p[1]; a2 += w3 * q[0]; a3 += w3 * q[1];
    }
    for (; j < c; ++j) {
        int r = col[start + j];
        float w = dinv[r];
        uint v = zu[(size_t)r * 64 + lane];
        f32x2 p = __builtin_amdgcn_cvt_pk_f32_fp8(v, 0);
        f32x2 q = __builtin_amdgcn_cvt_pk_f32_fp8(v, 1);
        a0 += w * p[0]; a1 += w * p[1]; a2 += w * q[0]; a3 += w * q[1];
    }

    // self-loop + norm + bias (+relu)
    uint vs = zu[(size_t)n * 64 + lane];
    f32x2 sp = __builtin_amdgcn_cvt_pk_f32_fp8(vs, 0);
    f32x2 sq = __builtin_amdgcn_cvt_pk_f32_fp8(vs, 1);
    float sv[4] = {sp[0], sp[1], sq[0], sq[1]};
    f32x4 bv = *(const f32x4*)(bias + lane * 4);
    ushort o[4];
#pragma unroll
    for (int i = 0; i < 4; ++i) {
        float acc = (i == 0 ? a0 : i == 1 ? a1 : i == 2 ? a2 : a3);
        float r = dv * (acc + dv * sv[i]) + bv[i];
        if (relu) r = fmaxf(r, 0.f);
        o[i] = f2bf(r);
    }
    *(s16x4*)(out + (size_t)n * HID + (size_t)lane * 4) = *(const s16x4*)o;
}

// ---------------- pool: segmented sum over sorted batch ----------------

__global__ __launch_bounds__(256) void pool_sum(const ushort* __restrict__ h,
                                                const int* __restrict__ batch,
                                                float* __restrict__ psum, int n) {
    int f = threadIdx.x;
    int r0 = blockIdx.x * 64;
    int rend = min(r0 + 64, n);
    if (r0 >= n) return;
    int g = batch[r0];
    float acc = 0.f;
    for (int r = r0; r < rend; ++r) {
        int gr = batch[r];
        if (gr != g) {
            atomicAdd(&psum[g * HID + f], acc);
            acc = 0.f;
            g = gr;
        }
        acc += bf2f(h[(size_t)r * HID + f]);
    }
    atomicAdd(&psum[g * HID + f], acc);
}

// ---------------- fused head ----------------

__global__ __launch_bounds__(256) void head_k(const float* __restrict__ psum,
                                              const int* __restrict__ batch, int n,
                                              const float* __restrict__ Wc1, const float* __restrict__ bc1,
                                              const float* __restrict__ Wc2, const float* __restrict__ bc2,
                                              const float* __restrict__ Wc3, const float* __restrict__ bc3,
                                              float* __restrict__ out) {
    int g = blockIdx.x;
    int t = threadIdx.x;
    __shared__ float pr[256];
    __shared__ float l1s[16], p1s[16];
    __shared__ float l2s[64], p2s[64];
    int lo = 0, hi = n;
    while (lo < hi) { int mid = (lo + hi) >> 1; if (batch[mid] < g) lo = mid + 1; else hi = mid; }
    int start = lo;
    lo = start; hi = n;
    while (lo < hi) { int mid = (lo + hi) >> 1; if (batch[mid] < g + 1) lo = mid + 1; else hi = mid; }
    int c = lo - start;
    float inv_c = 1.f / (float)max(c, 1);
    pr[t] = psum[g * 256 + t] * inv_c;
    __syncthreads();
    if (t < 16) {
        float a = bc1[t];
        for (int k = 0; k < 256; ++k) a += pr[k] * Wc1[k * 16 + t];
        l1s[t] = a;
        out[g * 16 + t] = a;
    }
    __syncthreads();
    if (t == 0) {
        float m = -1e30f;
        for (int j = 0; j < 16; ++j) m = fmaxf(m, l1s[j]);
        float s = 0.f;
        for (int j = 0; j < 16; ++j) { float e = expf(l1s[j] - m); p1s[j] = e; s += e; }
        float inv = 1.f / s;
        for (int j = 0; j < 16; ++j) p1s[j] *= inv;
    }
    __syncthreads();
    if (t < 64) {
        float a = bc2[t];
        for (int k = 0; k < 256; ++k) a += pr[k] * Wc2[k * 64 + t];
        for (int k = 0; k < 16; ++k) a += p1s[k] * Wc2[(256 + k) * 64 + t];
        l2s[t] = a;
        out[4096 + g * 64 + t] = a;
    }
    __syncthreads();
    if (t == 0) {
        float m = -1e30f;
        for (int j = 0; j < 64; ++j) m = fmaxf(m, l2s[j]);
        float s = 0.f;
        for (int j = 0; j < 64; ++j) { float e = expf(l2s[j] - m); p2s[j] = e; s += e; }
        float inv = 1.f / s;
        for (int j = 0; j < 64; ++j) p2s[j] *= inv;
    }
    __syncthreads();
    {
        float a = bc3[t];
        for (int k = 0; k < 256; ++k) a += pr[k] * Wc3[k * 256 + t];
        for (int k = 0; k < 64; ++k) a += p2s[k] * Wc3[(256 + k) * 256 + t];
        out[4096 + 16384 + g * 256 + t] = a;
    }
}

// ---------------- launch ----------------

extern "C" void kernel_launch(void* const* d_in, const int* in_sizes, int n_in,
                              void* d_out, int out_size, void* d_ws, size_t ws_size,
                              hipStream_t stream) {
    const float* x    = (const float*)d_in[0];
    const int*   ei   = (const int*)d_in[1];
    const int*   batch= (const int*)d_in[2];
    const float* W1 = (const float*)d_in[3];  const float* b1 = (const float*)d_in[4];
    const float* W2 = (const float*)d_in[5];  const float* b2 = (const float*)d_in[6];
    const float* W3 = (const float*)d_in[7];  const float* b3 = (const float*)d_in[8];
    const float* Wc1= (const float*)d_in[9];  const float* bc1= (const float*)d_in[10];
    const float* Wc2= (const float*)d_in[11]; const float* bc2= (const float*)d_in[12];
    const float* Wc3= (const float*)d_in[13]; const float* bc3= (const float*)d_in[14];
    float* out = (float*)d_out;

    const int N = N_NODES, E = N_EDGES, G = N_GRAPHS;

    char* ws = (char*)d_ws;
    size_t off = 0;
    auto alloc = [&](size_t bytes) -> void* {
        void* p = ws + off;
        off = (off + bytes + 255) & ~(size_t)255;
        return p;
    };
    unsigned char* z = (unsigned char*)alloc((size_t)ROWS_PAD * HID);      // 12.8 MB fp8
    ushort* hb   = (ushort*)alloc((size_t)ROWS_PAD * HID * 2);             // 25.6 MB bf16
    ushort* Wt1  = (ushort*)alloc((size_t)256 * 320 * 2);
    ushort* Wt2  = (ushort*)alloc((size_t)256 * 256 * 2);
    ushort* Wt3  = (ushort*)alloc((size_t)256 * 256 * 2);
    int*   cnt    = (int*)alloc((size_t)N * 4);
    int*   rp     = (int*)alloc((size_t)N * 4);
    int*   cursor = (int*)alloc((size_t)N * 4);
    float* dinv   = (float*)alloc((size_t)N * 4);
    int*   col    = (int*)alloc((size_t)E * 4);
    float* psum   = (float*)alloc((size_t)G * HID * 4);
    int*   bsums  = (int*)alloc(256 * 4);
    (void)ws_size;

    const int* src = ei;
    const int* dst = ei + E;

    hipMemsetAsync(cnt, 0, (size_t)N * 4, stream);
    hipMemsetAsync(psum, 0, (size_t)G * HID * 4, stream);
    count_deg<<<(E + 255) / 256, 256, 0, stream>>>(dst, cnt, E);
    const int NB = (N + 255) / 256;
    scan1<<<NB, 256, 0, stream>>>(cnt, rp, bsums, dinv, N);
    scan2<<<1, 256, 0, stream>>>(bsums, NB);
    scan3<<<NB, 256, 0, stream>>>(rp, cursor, bsums, N);
    fill_csr<<<(E + 255) / 256, 256, 0, stream>>>(src, dst, cursor, col, E);

    transpose_w3<<<832, 256, 0, stream>>>(W1, W2, W3, Wt1, Wt2, Wt3);

    const int MB = (N + 63) / 64;  // 782
    gemm_bf16<320, IN_DIM, true><<<MB, 256, 0, stream>>>(x, Wt1, z, N);
    aggregate_fp8<<<N / 4, 256, 0, stream>>>(z, hb, rp, cnt, col, dinv, b1, 1);
    gemm_bf16<256, 256, false><<<MB, 256, 0, stream>>>(hb, Wt2, z, N);
    aggregate_fp8<<<N / 4, 256, 0, stream>>>(z, hb, rp, cnt, col, dinv, b2, 1);
    gemm_bf16<256, 256, false><<<MB, 256, 0, stream>>>(hb, Wt3, z, N);
    aggregate_fp8<<<N / 4, 256, 0, stream>>>(z, hb, rp, cnt, col, dinv, b3, 0);

    pool_sum<<<MB, 256, 0, stream>>>(hb, batch, psum, N);
    head_k<<<G, 256, 0, stream>>>(psum, batch, N, Wc1, bc1, Wc2, bc2, Wc3, bc3, out);
}